// Round 14
// baseline (559.253 us; speedup 1.0000x reference)
//
#include <hip/hip_runtime.h>
#include <hip/hip_bf16.h>

constexpr int B  = 16;
constexpr int C  = 128;
constexpr int H  = 128;
constexpr int W  = 128;
constexpr int CO = 256;
constexpr int HO = 64;
constexpr int WO = 64;

#define EPSV   1e-8f
#define SLOPE  0.2f

typedef short bf16x8 __attribute__((ext_vector_type(8)));
typedef float f32x4  __attribute__((ext_vector_type(4)));

__device__ __forceinline__ short f2bs(float v) {
    __hip_bfloat16 h = __float2bfloat16(v);
    return *(short*)&h;
}
__device__ __forceinline__ float bs2f(short s) {
    __hip_bfloat16 h = *(__hip_bfloat16*)&s;
    return __bfloat162float(h);
}

// ---------------------------------------------------------------------------
// prep: fused dwexpand (blocks 0-2047) + demod x2-per-block (2048-4095).
// r14: nchw2nhwc removed — conv1 now stages NCHW f32 directly.
// ---------------------------------------------------------------------------
__global__ __launch_bounds__(256) void prep_kernel(
    const float* __restrict__ dw, short* __restrict__ dwm,
    const float* __restrict__ w1, const float* __restrict__ w2,
    const float* __restrict__ s1, const float* __restrict__ s2,
    float* __restrict__ d)
{
    int gb  = blockIdx.x;
    int tid = threadIdx.x;

    if (gb < 2048) {
        // ---- dwexpand: dwm[tap][ocT][icC][(oc&15)*32+(ic&31)] ----
        int idx = gb * 256 + tid;
        int ic  = idx & 127;
        int oc  = (idx >> 7) & 255;
        int tap = idx >> 15;
        int dst = ((tap * 16 + (oc >> 4)) * 4 + (ic >> 5)) * 512
                + (oc & 15) * 32 + (ic & 31);
        dwm[dst] = f2bs(dw[(oc * C + ic) * 16 + tap]);
    } else {
        // ---- demod: two outputs per block; half = tid>>7, ic = tid&127 ----
        int half = tid >> 7;
        int tl   = tid & 127;
        int bid  = (gb - 2048) * 2 + half;
        int conv = bid >> 11;
        int b    = (bid >> 7) & 15;
        int o    = bid & 127;
        const float* w = conv ? w2 : w1;
        const float* sv = conv ? s2 : s1;
        float svv = sv[b * C + tl] + 1.0f;
        const float* wp = w + (o * C + tl) * 9;
        float sum = 0.f;
        #pragma unroll
        for (int k = 0; k < 9; ++k) { float t = wp[k] * svv; sum += t * t; }
        #pragma unroll
        for (int off = 32; off; off >>= 1) sum += __shfl_down(sum, off);
        __shared__ float red[4];
        if ((tid & 63) == 0) red[tid >> 6] = sum;   // wave -> its slot
        __syncthreads();
        if ((tid & 127) == 0)
            d[bid] = rsqrtf(red[half * 2] + red[half * 2 + 1] + EPSV);
    }
}

// ---------------------------------------------------------------------------
// expand -> wave-coalesced B-fragment tiling (r8: 4 ic per thread,
// float4 style load + 8B packed store).
// wm[cb][tap][ocT=oc>>4][icC=ic>>5][(oc&15)*32 + (ic&31)]   (bf16)
// ---------------------------------------------------------------------------
__global__ __launch_bounds__(256) void expand_kernel(
    const float* __restrict__ w1, const float* __restrict__ w2,
    const float* __restrict__ s1, const float* __restrict__ s2,
    const float* __restrict__ d, short* __restrict__ wm)
{
    int idx = blockIdx.x * 256 + threadIdx.x;   // 288*128*32 = 1,179,648
    int icq = idx & 31;                          // ic quad index
    int oc  = (idx >> 5) & 127;
    int t   = idx >> 12;                         // cb*9+tap, < 288
    int tap = t % 9;
    int cb  = t / 9;                             // conv*16+b
    int b   = cb & 15;
    int conv= cb >> 4;
    const float* w = conv ? w2 : w1;
    const float* s = conv ? s2 : s1;
    int ic0 = icq * 4;

    float4 sv = *(const float4*)&s[b * C + ic0];
    float dv = d[(conv * B + b) * C + oc];
    const float* wp = w + (oc * C + ic0) * 9 + tap;

    short vs[4];
    vs[0] = f2bs(wp[ 0] * (sv.x + 1.0f) * dv);
    vs[1] = f2bs(wp[ 9] * (sv.y + 1.0f) * dv);
    vs[2] = f2bs(wp[18] * (sv.z + 1.0f) * dv);
    vs[3] = f2bs(wp[27] * (sv.w + 1.0f) * dv);

    int dst = cb * 147456
            + ((tap * 8 + (oc >> 4)) * 4 + (ic0 >> 5)) * 512
            + (oc & 15) * 32 + (ic0 & 31);
    *(uint2*)&wm[dst] = *(uint2*)vs;
}

// ---------------------------------------------------------------------------
// conv3x3 #1 — r14: fused NCHW->NHWC transpose into halo staging.
// Identical K-loop/epilogue to conv3x3_mfma (r11 form); only the staging
// reads NCHW f32 directly (90 guarded scalar load+cvt+store per thread,
// coalesced 18-float runs). Removes the standalone 192MB transpose kernel;
// adds +64MB f32 reads here (conv1 was at 15% HBM — headroom).
// TRIPWIRES: absmax>0.0625 = index bug; dur>130us = fusion uneconomical.
// ---------------------------------------------------------------------------
__global__ __launch_bounds__(256, 3) void conv3x3_nchw_mfma(
    const float* __restrict__ fin, const short* __restrict__ wmc,
    short* __restrict__ out)
{
    __shared__ short sIn[10 * 18 * 136];   // 48,960 B

    // T1: XCD-aware swizzle (r6).
    int bid0 = blockIdx.x;
    int bid  = (bid0 & 7) * 256 + (bid0 >> 3);

    int wt = bid & 7, ht = (bid >> 3) & 15, b = bid >> 7;
    int w0 = wt * 16, h0 = ht * 8;
    int tid  = threadIdx.x;
    int lane = tid & 63;
    int wv   = __builtin_amdgcn_readfirstlane(tid >> 6);   // SGPR wave idx
    int q = lane >> 4, l15 = lane & 15;

    // ---- staging: 10 rows x 18 w x 128 ic from NCHW f32 ----
    // j scan: wl inner (18-run coalescing), then ic, then row.
    for (int k = 0; k < 90; ++k) {
        int j  = tid + k * 256;        // j in [0, 23040)
        int wl = j % 18;
        int t  = j / 18;               // t = hl*128 + ic
        int ic = t & 127;
        int hl = t >> 7;
        int gh = h0 - 1 + hl, gw = w0 - 1 + wl;
        float v = 0.f;
        if ((unsigned)gh < (unsigned)H && (unsigned)gw < (unsigned)W)
            v = fin[((b * C + ic) * H + gh) * W + gw];
        sIn[(hl * 18 + wl) * 136 + ic] = f2bs(v);
    }
    __syncthreads();

    // SGPR base for this wave's weight frags; VGPR lane offset hoisted once.
    const short* wbW = wmc + b * 147456 + wv * 4096;
    int bfLane = l15 * 32 + q * 8;
    const short* afB = sIn + l15 * 136 + q * 8;

    f32x4 acc[8][2];
    #pragma unroll
    for (int mt = 0; mt < 8; ++mt)
        #pragma unroll
        for (int nt = 0; nt < 2; ++nt)
            acc[mt][nt] = (f32x4){0.f, 0.f, 0.f, 0.f};

    bf16x8 af[2][8];
    bf16x8 bf[2][2];

    auto ldAF = [&](int slot, int tap, int c) {
        int dh = tap / 3, dw = tap - dh * 3;
        #pragma unroll
        for (int mt = 0; mt < 8; ++mt)
            af[slot][mt] = *(const bf16x8*)(afB + (dh * 18 + dw) * 136 + c * 32
                                            + mt * 2448);
    };
    auto ldBF = [&](int slot, int tap, int c) {
        #pragma unroll
        for (int nt = 0; nt < 2; ++nt)
            bf[slot][nt] = *(const bf16x8*)(wbW + ((tap * 8 + nt) * 4 + c) * 512
                                            + bfLane);
    };

    ldAF(0, 0, 0);
    ldBF(0, 0, 0);

    #pragma unroll
    for (int s = 0; s < 36; ++s) {
        int s1 = (s + 1 < 36) ? s + 1 : s;
        ldBF((s + 1) & 1, s1 >> 2, s1 & 3);
        ldAF((s + 1) & 1, s1 >> 2, s1 & 3);
        __builtin_amdgcn_s_setprio(1);
        #pragma unroll
        for (int mt = 0; mt < 8; ++mt)
            #pragma unroll
            for (int nt = 0; nt < 2; ++nt)
                acc[mt][nt] = __builtin_amdgcn_mfma_f32_16x16x32_bf16(
                    af[s & 1][mt], bf[s & 1][nt], acc[mt][nt], 0, 0, 0);
        __builtin_amdgcn_s_setprio(0);
    }

    #pragma unroll
    for (int mt = 0; mt < 8; ++mt) {
        int h = h0 + mt;
        #pragma unroll
        for (int nt = 0; nt < 2; ++nt) {
            int oc = wv * 32 + nt * 16 + l15;
            #pragma unroll
            for (int reg = 0; reg < 4; ++reg) {
                int w = w0 + q * 4 + reg;
                int idx = ((b * H + h) * W + w) * C + oc;
                float v = acc[mt][nt][reg];
                v = v >= 0.f ? v : SLOPE * v;
                out[idx] = f2bs(v);
            }
        }
    }
}

// ---------------------------------------------------------------------------
// conv3x3 #2 — r11 configuration (counter-verified: ~105 us, MfmaUtil 30%,
// VGPR 80). NHWC bf16 input + residual. FROZEN.
// LESSONS: r5/r12 dist-2 null/regress; r7 barrier pipeline regress;
// r9 retile WIN (-22%); r11 SALU ~+4%.
// ---------------------------------------------------------------------------
__global__ __launch_bounds__(256, 3) void conv3x3_mfma(
    const short* __restrict__ in, const short* __restrict__ wmc,
    const short* __restrict__ res, short* __restrict__ out)
{
    __shared__ short sIn[10 * 18 * 136];   // 48,960 B

    int bid0 = blockIdx.x;
    int bid  = (bid0 & 7) * 256 + (bid0 >> 3);

    int wt = bid & 7, ht = (bid >> 3) & 15, b = bid >> 7;
    int w0 = wt * 16, h0 = ht * 8;
    int tid  = threadIdx.x;
    int lane = tid & 63;
    int wv   = __builtin_amdgcn_readfirstlane(tid >> 6);
    int q = lane >> 4, l15 = lane & 15;

    for (int i = tid; i < 10 * 18 * 16; i += 256) {
        int icg = i & 15;
        int t = i >> 4;
        int wl = t % 18, hl = t / 18;
        int gh = h0 - 1 + hl, gw = w0 - 1 + wl;
        uint4 v = make_uint4(0u, 0u, 0u, 0u);
        if ((unsigned)gh < (unsigned)H && (unsigned)gw < (unsigned)W)
            v = *(const uint4*)&in[((b * H + gh) * W + gw) * C + icg * 8];
        *(uint4*)&sIn[(hl * 18 + wl) * 136 + icg * 8] = v;
    }
    __syncthreads();

    const short* wbW = wmc + b * 147456 + wv * 4096;
    int bfLane = l15 * 32 + q * 8;
    const short* afB = sIn + l15 * 136 + q * 8;

    f32x4 acc[8][2];
    #pragma unroll
    for (int mt = 0; mt < 8; ++mt)
        #pragma unroll
        for (int nt = 0; nt < 2; ++nt)
            acc[mt][nt] = (f32x4){0.f, 0.f, 0.f, 0.f};

    bf16x8 af[2][8];
    bf16x8 bf[2][2];

    auto ldAF = [&](int slot, int tap, int c) {
        int dh = tap / 3, dw = tap - dh * 3;
        #pragma unroll
        for (int mt = 0; mt < 8; ++mt)
            af[slot][mt] = *(const bf16x8*)(afB + (dh * 18 + dw) * 136 + c * 32
                                            + mt * 2448);
    };
    auto ldBF = [&](int slot, int tap, int c) {
        #pragma unroll
        for (int nt = 0; nt < 2; ++nt)
            bf[slot][nt] = *(const bf16x8*)(wbW + ((tap * 8 + nt) * 4 + c) * 512
                                            + bfLane);
    };

    ldAF(0, 0, 0);
    ldBF(0, 0, 0);

    #pragma unroll
    for (int s = 0; s < 36; ++s) {
        int s1 = (s + 1 < 36) ? s + 1 : s;
        ldBF((s + 1) & 1, s1 >> 2, s1 & 3);
        ldAF((s + 1) & 1, s1 >> 2, s1 & 3);
        __builtin_amdgcn_s_setprio(1);
        #pragma unroll
        for (int mt = 0; mt < 8; ++mt)
            #pragma unroll
            for (int nt = 0; nt < 2; ++nt)
                acc[mt][nt] = __builtin_amdgcn_mfma_f32_16x16x32_bf16(
                    af[s & 1][mt], bf[s & 1][nt], acc[mt][nt], 0, 0, 0);
        __builtin_amdgcn_s_setprio(0);
    }

    bool has_res = (res != nullptr);
    #pragma unroll
    for (int mt = 0; mt < 8; ++mt) {
        int h = h0 + mt;
        #pragma unroll
        for (int nt = 0; nt < 2; ++nt) {
            int oc = wv * 32 + nt * 16 + l15;
            #pragma unroll
            for (int reg = 0; reg < 4; ++reg) {
                int w = w0 + q * 4 + reg;
                int idx = ((b * H + h) * W + w) * C + oc;
                float v = acc[mt][nt][reg];
                if (has_res) v += bs2f(res[idx]);
                v = v >= 0.f ? v : SLOPE * v;
                out[idx] = f2bs(v);
            }
        }
    }
}

// ---------------------------------------------------------------------------
// downconv MFMA — r10 retile + r11 SALU addressing. FROZEN.
// LESSONS: r1 spill, r3 restructure regress, r4 setprio WIN, r10 retile WIN.
// ---------------------------------------------------------------------------
__global__ __launch_bounds__(256, 2) void downconv_mfma(
    const short* __restrict__ in, const short* __restrict__ dwm,
    const float* __restrict__ db, float* __restrict__ out)
{
    __shared__ short sIn[19 * 2 * 18 * 40];   // 54,720 B

    int bid = blockIdx.x;
    int wt = bid & 3;  bid >>= 2;
    int ht = bid & 7;  bid >>= 3;
    int ot = bid & 1;  bid >>= 1;
    int b  = bid;
    int ow0 = wt * 16, oh0 = ht * 8, oc0 = ot * 128;

    int tid  = threadIdx.x;
    int lane = tid & 63;
    int wv   = __builtin_amdgcn_readfirstlane(tid >> 6);
    int q = lane >> 4, l15 = lane & 15;

    f32x4 acc[2][8];
    #pragma unroll
    for (int mt = 0; mt < 2; ++mt)
        #pragma unroll
        for (int nt = 0; nt < 8; ++nt)
            acc[mt][nt] = (f32x4){0.f, 0.f, 0.f, 0.f};

    int ocTb = ot * 8 + wv * 2;

    for (int i = tid; i < 19 * 35 * 4; i += 256) {
        int icg = i & 3;
        int t = i >> 2;
        int wl = t % 35, hl = t / 35;
        int gh = 2 * oh0 - 1 + hl, gw = 2 * ow0 - 1 + wl;
        uint4 v = make_uint4(0u, 0u, 0u, 0u);
        if ((unsigned)gh < (unsigned)H && (unsigned)gw < (unsigned)W)
            v = *(const uint4*)&in[((b * H + gh) * W + gw) * C + icg * 8];
        *(uint4*)&sIn[((hl * 2 + (wl & 1)) * 18 + (wl >> 1)) * 40 + icg * 8] = v;
    }

    const short* dwW = dwm + ocTb * 2048;
    int dwLane = l15 * 32 + q * 8;
    const short* bfB = sIn + l15 * 40 + q * 8;

    bf16x8 af[4][2];
    bf16x8 bf[2][8];

    #pragma unroll
    for (int s = 0; s < 3; ++s)
        #pragma unroll
        for (int mt = 0; mt < 2; ++mt)
            af[s][mt] = *(const bf16x8*)(dwW + (s * 16 + mt) * 2048 + dwLane);

    __syncthreads();

    #pragma unroll 1
    for (int c = 0; c < 4; ++c) {
        #pragma unroll
        for (int nt = 0; nt < 8; ++nt)
            bf[0][nt] = *(const bf16x8*)(bfB + (2 * nt) * 2 * 18 * 40);

        #pragma unroll
        for (int tap = 0; tap < 16; ++tap) {
            {
                int sp = c * 16 + tap + 3;
                sp = sp < 63 ? sp : 63;
                int pc = sp >> 4, pt = sp & 15;
                #pragma unroll
                for (int mt = 0; mt < 2; ++mt)
                    af[(tap + 3) & 3][mt] =
                        *(const bf16x8*)(dwW + (pt * 16 + mt) * 2048 + pc * 512
                                         + dwLane);
            }
            {
                int tapn = (tap + 1 < 16) ? tap + 1 : tap;
                int dhn = tapn >> 2, dwn = tapn & 3;
                #pragma unroll
                for (int nt = 0; nt < 8; ++nt) {
                    int hl = 2 * nt + dhn;
                    bf[(tap + 1) & 1][nt] =
                        *(const bf16x8*)(bfB + ((hl * 2 + (dwn & 1)) * 18
                                                + (dwn >> 1)) * 40);
                }
            }
            __builtin_amdgcn_s_setprio(1);
            #pragma unroll
            for (int mt = 0; mt < 2; ++mt)
                #pragma unroll
                for (int nt = 0; nt < 8; ++nt)
                    acc[mt][nt] = __builtin_amdgcn_mfma_f32_16x16x32_bf16(
                        af[tap & 3][mt], bf[tap & 1][nt], acc[mt][nt], 0, 0, 0);
            __builtin_amdgcn_s_setprio(0);
        }

        if (c < 3) {
            __syncthreads();
            for (int i = tid; i < 19 * 35 * 4; i += 256) {
                int icg = i & 3;
                int t = i >> 2;
                int wl = t % 35, hl = t / 35;
                int gh = 2 * oh0 - 1 + hl, gw = 2 * ow0 - 1 + wl;
                uint4 v = make_uint4(0u, 0u, 0u, 0u);
                if ((unsigned)gh < (unsigned)H && (unsigned)gw < (unsigned)W)
                    v = *(const uint4*)&in[((b * H + gh) * W + gw) * C
                                           + (c + 1) * 32 + icg * 8];
                *(uint4*)&sIn[((hl * 2 + (wl & 1)) * 18 + (wl >> 1)) * 40 + icg * 8] = v;
            }
            __syncthreads();
        }
    }

    #pragma unroll
    for (int mt = 0; mt < 2; ++mt) {
        #pragma unroll
        for (int reg = 0; reg < 4; ++reg) {
            int oc = oc0 + wv * 32 + mt * 16 + q * 4 + reg;
            float bias = db[oc];
            #pragma unroll
            for (int nt = 0; nt < 8; ++nt) {
                int oh = oh0 + nt;
                int ow = ow0 + l15;
                out[((b * CO + oc) * HO + oh) * WO + ow] = acc[mt][nt][reg] + bias;
            }
        }
    }
}

// ---------------------------------------------------------------------------
extern "C" void kernel_launch(void* const* d_in, const int* in_sizes, int n_in,
                              void* d_out, int out_size, void* d_ws, size_t ws_size,
                              hipStream_t stream) {
    const float* features = (const float*)d_in[0];
    const float* sm1      = (const float*)d_in[1];   // style_mean1 -> s1
    const float* ss1      = (const float*)d_in[2];   // style_std1  -> s2 (per reference)
    const float* w1       = (const float*)d_in[6];
    const float* w2       = (const float*)d_in[7];
    const float* dw       = (const float*)d_in[8];
    const float* db       = (const float*)d_in[9];
    float* out = (float*)d_out;

    char* ws = (char*)d_ws;
    short* x1  = (short*)ws;                              // 67,108,864 B
    short* x2  = (short*)(ws + 67108864);                 // 67,108,864 B
    short* wm  = (short*)(ws + 134217728);                // 9,437,184 B
    short* dwm = (short*)(ws + 143654912);                // 1,048,576 B
    float* dv  = (float*)(ws + 144703488);                // 16,384 B

    // prep: dwexpand (0-2047) + demod x2 (2048-4095)
    prep_kernel       <<<4096, 256, 0, stream>>>(dw, dwm, w1, w2, sm1, ss1, dv);
    expand_kernel     <<<4608, 256, 0, stream>>>(w1, w2, sm1, ss1, dv, wm);
    // conv1: fused NCHW f32 read (transpose folded into halo staging)
    conv3x3_nchw_mfma <<<2048, 256, 0, stream>>>(features, wm, x1);
    conv3x3_mfma      <<<2048, 256, 0, stream>>>(x1, wm + 16 * 147456, x1, x2);
    downconv_mfma     <<<1024, 256, 0, stream>>>(x2, dwm, db, out);
}

// Round 15
// 461.621 us; speedup vs baseline: 1.2115x; 1.2115x over previous
//
#include <hip/hip_runtime.h>
#include <hip/hip_bf16.h>

constexpr int B  = 16;
constexpr int C  = 128;
constexpr int H  = 128;
constexpr int W  = 128;
constexpr int CO = 256;
constexpr int HO = 64;
constexpr int WO = 64;

#define EPSV   1e-8f
#define SLOPE  0.2f

typedef short bf16x8 __attribute__((ext_vector_type(8)));
typedef float f32x4  __attribute__((ext_vector_type(4)));

__device__ __forceinline__ short f2bs(float v) {
    __hip_bfloat16 h = __float2bfloat16(v);
    return *(short*)&h;
}
__device__ __forceinline__ float bs2f(short s) {
    __hip_bfloat16 h = *(__hip_bfloat16*)&s;
    return __bfloat162float(h);
}

// ---------------------------------------------------------------------------
// prep: fused nchw2nhwc (blocks 0-2047) + dwexpand (2048-4095)
//       + demod (4096-6143, TWO outputs/block — all 256 lanes active).
// r14 LESSON: fusing the transpose into conv1's halo staging REGRESSED
// (106->222us: 23040 scalar 2B LDS stores/block, bank-conflict 9.4M->12.2M).
// The dedicated float4/uint4 transpose kernel is the right structure.
// ---------------------------------------------------------------------------
__global__ __launch_bounds__(256) void prep_kernel(
    const float* __restrict__ in, short* __restrict__ outNhwc,
    const float* __restrict__ dw, short* __restrict__ dwm,
    const float* __restrict__ w1, const float* __restrict__ w2,
    const float* __restrict__ s1, const float* __restrict__ s2,
    float* __restrict__ d)
{
    __shared__ short s[128 * 136];
    int gb  = blockIdx.x;
    int tid = threadIdx.x;

    if (gb < 2048) {
        // ---- nchw(f32) -> nhwc(bf16) transpose ----
        int h = gb & 127, b = gb >> 7;
        for (int i = tid; i < 128 * 32; i += 256) {
            int w4 = i & 31, ic = i >> 5;
            float4 v = *(const float4*)&in[((b * C + ic) * H + h) * W + w4 * 4];
            s[(w4 * 4 + 0) * 136 + ic] = f2bs(v.x);
            s[(w4 * 4 + 1) * 136 + ic] = f2bs(v.y);
            s[(w4 * 4 + 2) * 136 + ic] = f2bs(v.z);
            s[(w4 * 4 + 3) * 136 + ic] = f2bs(v.w);
        }
        __syncthreads();
        for (int i = tid; i < 128 * 16; i += 256) {
            int icg = i & 15, w = i >> 4;
            *(uint4*)&outNhwc[((b * H + h) * W + w) * C + icg * 8] =
                *(uint4*)&s[w * 136 + icg * 8];
        }
    } else if (gb < 4096) {
        // ---- dwexpand: dwm[tap][ocT][icC][(oc&15)*32+(ic&31)] ----
        int idx = (gb - 2048) * 256 + tid;
        int ic  = idx & 127;
        int oc  = (idx >> 7) & 255;
        int tap = idx >> 15;
        int dst = ((tap * 16 + (oc >> 4)) * 4 + (ic >> 5)) * 512
                + (oc & 15) * 32 + (ic & 31);
        dwm[dst] = f2bs(dw[(oc * C + ic) * 16 + tap]);
    } else {
        // ---- demod: two outputs per block; half = tid>>7, ic = tid&127 ----
        int half = tid >> 7;
        int tl   = tid & 127;
        int bid  = (gb - 4096) * 2 + half;
        int conv = bid >> 11;
        int b    = (bid >> 7) & 15;
        int o    = bid & 127;
        const float* w = conv ? w2 : w1;
        const float* sv = conv ? s2 : s1;
        float svv = sv[b * C + tl] + 1.0f;
        const float* wp = w + (o * C + tl) * 9;
        float sum = 0.f;
        #pragma unroll
        for (int k = 0; k < 9; ++k) { float t = wp[k] * svv; sum += t * t; }
        #pragma unroll
        for (int off = 32; off; off >>= 1) sum += __shfl_down(sum, off);
        __shared__ float red[4];
        if ((tid & 63) == 0) red[tid >> 6] = sum;   // wave -> its slot
        __syncthreads();
        if ((tid & 127) == 0)
            d[bid] = rsqrtf(red[half * 2] + red[half * 2 + 1] + EPSV);
    }
}

// ---------------------------------------------------------------------------
// expand -> wave-coalesced B-fragment tiling (r15: 8 ic per thread,
// 2x float4 style load + 16B uint4 store; grid 2304).
// wm[cb][tap][ocT=oc>>4][icC=ic>>5][(oc&15)*32 + (ic&31)]   (bf16)
// ---------------------------------------------------------------------------
__global__ __launch_bounds__(256) void expand_kernel(
    const float* __restrict__ w1, const float* __restrict__ w2,
    const float* __restrict__ s1, const float* __restrict__ s2,
    const float* __restrict__ d, short* __restrict__ wm)
{
    int idx = blockIdx.x * 256 + threadIdx.x;   // 288*128*16 = 589,824
    int ico = idx & 15;                          // ic octet index
    int oc  = (idx >> 4) & 127;
    int t   = idx >> 11;                         // cb*9+tap, < 288
    int tap = t % 9;
    int cb  = t / 9;                             // conv*16+b
    int b   = cb & 15;
    int conv= cb >> 4;
    const float* w = conv ? w2 : w1;
    const float* s = conv ? s2 : s1;
    int ic0 = ico * 8;

    float4 sv0 = *(const float4*)&s[b * C + ic0];
    float4 sv1 = *(const float4*)&s[b * C + ic0 + 4];
    float dv = d[(conv * B + b) * C + oc];
    const float* wp = w + (oc * C + ic0) * 9 + tap;

    short vs[8];
    vs[0] = f2bs(wp[ 0] * (sv0.x + 1.0f) * dv);
    vs[1] = f2bs(wp[ 9] * (sv0.y + 1.0f) * dv);
    vs[2] = f2bs(wp[18] * (sv0.z + 1.0f) * dv);
    vs[3] = f2bs(wp[27] * (sv0.w + 1.0f) * dv);
    vs[4] = f2bs(wp[36] * (sv1.x + 1.0f) * dv);
    vs[5] = f2bs(wp[45] * (sv1.y + 1.0f) * dv);
    vs[6] = f2bs(wp[54] * (sv1.z + 1.0f) * dv);
    vs[7] = f2bs(wp[63] * (sv1.w + 1.0f) * dv);

    int dst = cb * 147456
            + ((tap * 8 + (oc >> 4)) * 4 + (ic0 >> 5)) * 512
            + (oc & 15) * 32 + (ic0 & 31);
    *(uint4*)&wm[dst] = *(uint4*)vs;
}

// ---------------------------------------------------------------------------
// conv3x3 MFMA implicit GEMM — r11 configuration (counter-verified best:
// ~106 us, MfmaUtil 31%, VGPR 80). r9 retile (wave = 128px x 32oc,
// dedup'd weight loads) + r11 SALU addressing + T5 setprio + T1 swizzle.
// LESSONS (do not regress):
//  r5/r12: bf prefetch distance 2 null/REGRESS at BOTH tilings.
//  r7: per-step barrier pipeline REGRESS (36 vmcnt(0) drains unamortized).
//  r14: NCHW staging fusion REGRESS (scalar LDS stores, 222us).
//  r9: retile WIN (-22%); r11: SALU addressing ~+4%.
// ---------------------------------------------------------------------------
__global__ __launch_bounds__(256, 3) void conv3x3_mfma(
    const short* __restrict__ in, const short* __restrict__ wmc,
    const short* __restrict__ res, short* __restrict__ out)
{
    __shared__ short sIn[10 * 18 * 136];   // 48,960 B

    // T1: XCD-aware swizzle (r6: weights L2-resident per XCD; keep).
    int bid0 = blockIdx.x;
    int bid  = (bid0 & 7) * 256 + (bid0 >> 3);

    int wt = bid & 7, ht = (bid >> 3) & 15, b = bid >> 7;
    int w0 = wt * 16, h0 = ht * 8;
    int tid  = threadIdx.x;
    int lane = tid & 63;
    int wv   = __builtin_amdgcn_readfirstlane(tid >> 6);   // SGPR wave idx
    int q = lane >> 4, l15 = lane & 15;

    for (int i = tid; i < 10 * 18 * 16; i += 256) {
        int icg = i & 15;
        int t = i >> 4;
        int wl = t % 18, hl = t / 18;
        int gh = h0 - 1 + hl, gw = w0 - 1 + wl;
        uint4 v = make_uint4(0u, 0u, 0u, 0u);
        if ((unsigned)gh < (unsigned)H && (unsigned)gw < (unsigned)W)
            v = *(const uint4*)&in[((b * H + gh) * W + gw) * C + icg * 8];
        *(uint4*)&sIn[(hl * 18 + wl) * 136 + icg * 8] = v;
    }
    __syncthreads();

    // SGPR base for this wave's weight frags; VGPR lane offset hoisted once.
    const short* wbW = wmc + b * 147456 + wv * 4096;   // (wv*2 frags)*4c*512
    int bfLane = l15 * 32 + q * 8;                      // invariant VGPR
    const short* afB = sIn + l15 * 136 + q * 8;         // invariant LDS base

    f32x4 acc[8][2];
    #pragma unroll
    for (int mt = 0; mt < 8; ++mt)
        #pragma unroll
        for (int nt = 0; nt < 2; ++nt)
            acc[mt][nt] = (f32x4){0.f, 0.f, 0.f, 0.f};

    bf16x8 af[2][8];   // pixels (LDS), parity s&1, distance 1; 8 h-rows
    bf16x8 bf[2][2];   // weights (global), parity s&1, distance 1; 2 oc-tiles

    // K-step s = tap*4 + c  (tap = s>>2, c = s&3)
    auto ldAF = [&](int slot, int tap, int c) {
        int dh = tap / 3, dw = tap - dh * 3;
        #pragma unroll
        for (int mt = 0; mt < 8; ++mt)
            af[slot][mt] = *(const bf16x8*)(afB + (dh * 18 + dw) * 136 + c * 32
                                            + mt * 2448);
    };
    auto ldBF = [&](int slot, int tap, int c) {
        #pragma unroll
        for (int nt = 0; nt < 2; ++nt)
            bf[slot][nt] = *(const bf16x8*)(wbW + ((tap * 8 + nt) * 4 + c) * 512
                                            + bfLane);
    };

    // prologue: step 0 operands
    ldAF(0, 0, 0);
    ldBF(0, 0, 0);

    #pragma unroll
    for (int s = 0; s < 36; ++s) {
        // prefetch step s+1 (global first: longer latency)
        int s1 = (s + 1 < 36) ? s + 1 : s;       // dummy at tail
        ldBF((s + 1) & 1, s1 >> 2, s1 & 3);
        ldAF((s + 1) & 1, s1 >> 2, s1 & 3);
        // compute step s (T5)
        __builtin_amdgcn_s_setprio(1);
        #pragma unroll
        for (int mt = 0; mt < 8; ++mt)
            #pragma unroll
            for (int nt = 0; nt < 2; ++nt)
                acc[mt][nt] = __builtin_amdgcn_mfma_f32_16x16x32_bf16(
                    af[s & 1][mt], bf[s & 1][nt], acc[mt][nt], 0, 0, 0);
        __builtin_amdgcn_s_setprio(0);
    }

    bool has_res = (res != nullptr);
    #pragma unroll
    for (int mt = 0; mt < 8; ++mt) {
        int h = h0 + mt;
        #pragma unroll
        for (int nt = 0; nt < 2; ++nt) {
            int oc = wv * 32 + nt * 16 + l15;
            #pragma unroll
            for (int reg = 0; reg < 4; ++reg) {
                int w = w0 + q * 4 + reg;
                int idx = ((b * H + h) * W + w) * C + oc;
                float v = acc[mt][nt][reg];
                if (has_res) v += bs2f(res[idx]);
                v = v >= 0.f ? v : SLOPE * v;
                out[idx] = f2bs(v);
            }
        }
    }
}

// ---------------------------------------------------------------------------
// downconv MFMA — r10 retile + r11 SALU addressing. FROZEN.
// LESSONS: r1 spill, r3 restructure regress, r4 setprio WIN, r10 retile WIN.
// ---------------------------------------------------------------------------
__global__ __launch_bounds__(256, 2) void downconv_mfma(
    const short* __restrict__ in, const short* __restrict__ dwm,
    const float* __restrict__ db, float* __restrict__ out)
{
    __shared__ short sIn[19 * 2 * 18 * 40];   // 54,720 B

    int bid = blockIdx.x;
    int wt = bid & 3;  bid >>= 2;
    int ht = bid & 7;  bid >>= 3;
    int ot = bid & 1;  bid >>= 1;
    int b  = bid;
    int ow0 = wt * 16, oh0 = ht * 8, oc0 = ot * 128;

    int tid  = threadIdx.x;
    int lane = tid & 63;
    int wv   = __builtin_amdgcn_readfirstlane(tid >> 6);
    int q = lane >> 4, l15 = lane & 15;

    f32x4 acc[2][8];
    #pragma unroll
    for (int mt = 0; mt < 2; ++mt)
        #pragma unroll
        for (int nt = 0; nt < 8; ++nt)
            acc[mt][nt] = (f32x4){0.f, 0.f, 0.f, 0.f};

    int ocTb = ot * 8 + wv * 2;

    for (int i = tid; i < 19 * 35 * 4; i += 256) {
        int icg = i & 3;
        int t = i >> 2;
        int wl = t % 35, hl = t / 35;
        int gh = 2 * oh0 - 1 + hl, gw = 2 * ow0 - 1 + wl;
        uint4 v = make_uint4(0u, 0u, 0u, 0u);
        if ((unsigned)gh < (unsigned)H && (unsigned)gw < (unsigned)W)
            v = *(const uint4*)&in[((b * H + gh) * W + gw) * C + icg * 8];
        *(uint4*)&sIn[((hl * 2 + (wl & 1)) * 18 + (wl >> 1)) * 40 + icg * 8] = v;
    }

    const short* dwW = dwm + ocTb * 2048;
    int dwLane = l15 * 32 + q * 8;
    const short* bfB = sIn + l15 * 40 + q * 8;

    bf16x8 af[4][2];
    bf16x8 bf[2][8];

    #pragma unroll
    for (int s = 0; s < 3; ++s)
        #pragma unroll
        for (int mt = 0; mt < 2; ++mt)
            af[s][mt] = *(const bf16x8*)(dwW + (s * 16 + mt) * 2048 + dwLane);

    __syncthreads();

    #pragma unroll 1
    for (int c = 0; c < 4; ++c) {
        #pragma unroll
        for (int nt = 0; nt < 8; ++nt)
            bf[0][nt] = *(const bf16x8*)(bfB + (2 * nt) * 2 * 18 * 40);

        #pragma unroll
        for (int tap = 0; tap < 16; ++tap) {
            {
                int sp = c * 16 + tap + 3;
                sp = sp < 63 ? sp : 63;
                int pc = sp >> 4, pt = sp & 15;
                #pragma unroll
                for (int mt = 0; mt < 2; ++mt)
                    af[(tap + 3) & 3][mt] =
                        *(const bf16x8*)(dwW + (pt * 16 + mt) * 2048 + pc * 512
                                         + dwLane);
            }
            {
                int tapn = (tap + 1 < 16) ? tap + 1 : tap;
                int dhn = tapn >> 2, dwn = tapn & 3;
                #pragma unroll
                for (int nt = 0; nt < 8; ++nt) {
                    int hl = 2 * nt + dhn;
                    bf[(tap + 1) & 1][nt] =
                        *(const bf16x8*)(bfB + ((hl * 2 + (dwn & 1)) * 18
                                                + (dwn >> 1)) * 40);
                }
            }
            __builtin_amdgcn_s_setprio(1);
            #pragma unroll
            for (int mt = 0; mt < 2; ++mt)
                #pragma unroll
                for (int nt = 0; nt < 8; ++nt)
                    acc[mt][nt] = __builtin_amdgcn_mfma_f32_16x16x32_bf16(
                        af[tap & 3][mt], bf[tap & 1][nt], acc[mt][nt], 0, 0, 0);
            __builtin_amdgcn_s_setprio(0);
        }

        if (c < 3) {
            __syncthreads();
            for (int i = tid; i < 19 * 35 * 4; i += 256) {
                int icg = i & 3;
                int t = i >> 2;
                int wl = t % 35, hl = t / 35;
                int gh = 2 * oh0 - 1 + hl, gw = 2 * ow0 - 1 + wl;
                uint4 v = make_uint4(0u, 0u, 0u, 0u);
                if ((unsigned)gh < (unsigned)H && (unsigned)gw < (unsigned)W)
                    v = *(const uint4*)&in[((b * H + gh) * W + gw) * C
                                           + (c + 1) * 32 + icg * 8];
                *(uint4*)&sIn[((hl * 2 + (wl & 1)) * 18 + (wl >> 1)) * 40 + icg * 8] = v;
            }
            __syncthreads();
        }
    }

    #pragma unroll
    for (int mt = 0; mt < 2; ++mt) {
        #pragma unroll
        for (int reg = 0; reg < 4; ++reg) {
            int oc = oc0 + wv * 32 + mt * 16 + q * 4 + reg;
            float bias = db[oc];
            #pragma unroll
            for (int nt = 0; nt < 8; ++nt) {
                int oh = oh0 + nt;
                int ow = ow0 + l15;
                out[((b * CO + oc) * HO + oh) * WO + ow] = acc[mt][nt][reg] + bias;
            }
        }
    }
}

// ---------------------------------------------------------------------------
extern "C" void kernel_launch(void* const* d_in, const int* in_sizes, int n_in,
                              void* d_out, int out_size, void* d_ws, size_t ws_size,
                              hipStream_t stream) {
    const float* features = (const float*)d_in[0];
    const float* sm1      = (const float*)d_in[1];   // style_mean1 -> s1
    const float* ss1      = (const float*)d_in[2];   // style_std1  -> s2 (per reference)
    const float* w1       = (const float*)d_in[6];
    const float* w2       = (const float*)d_in[7];
    const float* dw       = (const float*)d_in[8];
    const float* db       = (const float*)d_in[9];
    float* out = (float*)d_out;

    char* ws = (char*)d_ws;
    short* x1  = (short*)ws;                              // 67,108,864 B
    short* x2  = (short*)(ws + 67108864);                 // 67,108,864 B
    short* wm  = (short*)(ws + 134217728);                // 9,437,184 B
    short* dwm = (short*)(ws + 143654912);                // 1,048,576 B
    float* dv  = (float*)(ws + 144703488);                // 16,384 B

    // prep: nchw2nhwc (0-2047) + dwexpand (2048-4095) + demod x2 (4096-6143)
    prep_kernel   <<<6144, 256, 0, stream>>>(features, x2, dw, dwm,
                                             w1, w2, sm1, ss1, dv);
    expand_kernel <<<2304, 256, 0, stream>>>(w1, w2, sm1, ss1, dv, wm);
    conv3x3_mfma  <<<2048, 256, 0, stream>>>(x2, wm, nullptr, x1);
    conv3x3_mfma  <<<2048, 256, 0, stream>>>(x1, wm + 16 * 147456, x1, x2);
    downconv_mfma <<<1024, 256, 0, stream>>>(x2, dwm, db, out);
}